// Round 1
// baseline (1796.878 us; speedup 1.0000x reference)
//
#include <hip/hip_runtime.h>
#include <cmath>

typedef _Float16 f16;
typedef _Float16 f16x8 __attribute__((ext_vector_type(8)));
typedef _Float16 f16x4 __attribute__((ext_vector_type(4)));
typedef float f32x4 __attribute__((ext_vector_type(4)));

#define MFMA16(a, b, c) __builtin_amdgcn_mfma_f32_16x16x32_f16(a, b, c, 0, 0, 0)

static constexpr int Bsz = 4;
static constexpr int T = 2048;
static constexpr int V = 2048;
static constexpr int D = 256;
static constexpr int R = 512;
static constexpr int M = Bsz * T;   // 8192

// ---------------------------------------------------------------- convert
__global__ __launch_bounds__(256) void conv_f32_f16(const float* __restrict__ src,
                                                    f16* __restrict__ dst, int n) {
    int idx = (blockIdx.x * 256 + threadIdx.x) * 4;
    if (idx < n) {
        float4 v = *(const float4*)&src[idx];
        f16x4 o;
        o[0] = (f16)v.x; o[1] = (f16)v.y; o[2] = (f16)v.z; o[3] = (f16)v.w;
        *(f16x4*)&dst[idx] = o;
    }
}

// ---------------------------------------------------------------- rmsnorm
__global__ __launch_bounds__(256) void rmsnorm_kernel(const float* __restrict__ x,
                                                      f16* __restrict__ out) {
    int row = blockIdx.x;
    const float* xr = x + (size_t)row * V;
    int tid = threadIdx.x;
    float4 v0 = ((const float4*)xr)[tid];
    float4 v1 = ((const float4*)xr)[tid + 256];
    float ss = v0.x * v0.x + v0.y * v0.y + v0.z * v0.z + v0.w * v0.w
             + v1.x * v1.x + v1.y * v1.y + v1.z * v1.z + v1.w * v1.w;
    for (int o = 32; o > 0; o >>= 1) ss += __shfl_xor(ss, o);
    __shared__ float wsum[4];
    if ((tid & 63) == 0) wsum[tid >> 6] = ss;
    __syncthreads();
    float tot = wsum[0] + wsum[1] + wsum[2] + wsum[3];
    float s = rsqrtf(tot / (float)V + 1.1920929e-07f);
    f16* orow = out + (size_t)row * V;
    f16x4 o0, o1;
    o0[0] = (f16)(v0.x * s); o0[1] = (f16)(v0.y * s);
    o0[2] = (f16)(v0.z * s); o0[3] = (f16)(v0.w * s);
    o1[0] = (f16)(v1.x * s); o1[1] = (f16)(v1.y * s);
    o1[2] = (f16)(v1.z * s); o1[3] = (f16)(v1.w * s);
    *(f16x4*)&orow[tid * 4] = o0;
    *(f16x4*)&orow[1024 + tid * 4] = o1;
}

// ---------------------------------------------------------------- GEMM NT
// C[m,n] = sum_k A[m,k]*B[n,k];  A: MxK row-major f16, B: NxK row-major f16
// mode 0: qkv route (N=768): cols 0-255 -> q, 256-511 -> k, 512-767 -> vT
// mode 1: outf = resid + sA*sB*C          (x2 = x + qs*qos*C)
// mode 2: out_h = gelu(C + bias[n])       (f16)
// mode 3: outf = resid + sA*sB*C          (d_out = x2 + ts*tos*C)
struct GemmEpi {
    int mode;
    const float* resid;
    float* outf;
    f16* out_q; f16* out_k; f16* out_vT;
    f16* out_h;
    const float* bias;
    const float* sA; const float* sB;
};

__global__ __launch_bounds__(256) void gemm_nt(const f16* __restrict__ A,
                                               const f16* __restrict__ Bm,
                                               int K, GemmEpi e) {
    __shared__ f16 Asl[128 * 40];
    __shared__ f16 Bsl[128 * 40];
    int tid = threadIdx.x;
    int lane = tid & 63, wv = tid >> 6;
    int wm = wv >> 1, wn = wv & 1;
    int quad = lane >> 4, l16 = lane & 15;
    int m0 = blockIdx.x * 128, n0 = blockIdx.y * 128;
    f32x4 acc[4][4] = {};
    int r = tid >> 2, c8 = (tid & 3) << 3;

    for (int k0 = 0; k0 < K; k0 += 32) {
        f16x8 a0 = *(const f16x8*)&A[(size_t)(m0 + r) * K + k0 + c8];
        f16x8 a1 = *(const f16x8*)&A[(size_t)(m0 + r + 64) * K + k0 + c8];
        f16x8 b0 = *(const f16x8*)&Bm[(size_t)(n0 + r) * K + k0 + c8];
        f16x8 b1 = *(const f16x8*)&Bm[(size_t)(n0 + r + 64) * K + k0 + c8];
        __syncthreads();
        *(f16x8*)&Asl[r * 40 + c8] = a0;
        *(f16x8*)&Asl[(r + 64) * 40 + c8] = a1;
        *(f16x8*)&Bsl[r * 40 + c8] = b0;
        *(f16x8*)&Bsl[(r + 64) * 40 + c8] = b1;
        __syncthreads();
        f16x8 af[4], bf[4];
        for (int i = 0; i < 4; i++)
            af[i] = *(const f16x8*)&Asl[(64 * wm + 16 * i + l16) * 40 + quad * 8];
        for (int i = 0; i < 4; i++)
            bf[i] = *(const f16x8*)&Bsl[(64 * wn + 16 * i + l16) * 40 + quad * 8];
        for (int mi = 0; mi < 4; mi++)
            for (int ni = 0; ni < 4; ni++)
                acc[mi][ni] = MFMA16(af[mi], bf[ni], acc[mi][ni]);
    }

    float s = 0.f;
    if (e.mode == 1 || e.mode == 3) s = e.sA[0] * e.sB[0];
    for (int mi = 0; mi < 4; mi++) {
        for (int ni = 0; ni < 4; ni++) {
            int ml = 64 * wm + 16 * mi + quad * 4;
            int nl = 64 * wn + 16 * ni + l16;
            int gn = n0 + nl;
            for (int i = 0; i < 4; i++) {
                int gm = m0 + ml + i;
                float vv = acc[mi][ni][i];
                if (e.mode == 0) {
                    if (gn < 256) {
                        e.out_q[(size_t)gm * D + gn] = (f16)vv;
                    } else if (gn < 512) {
                        e.out_k[(size_t)gm * D + (gn - 256)] = (f16)vv;
                    } else {
                        int d = gn - 512;
                        int b = gm >> 11, t = gm & 2047;
                        e.out_vT[((size_t)b * D + d) * T + t] = (f16)vv;
                    }
                } else if (e.mode == 1) {
                    size_t o = (size_t)gm * V + gn;
                    e.outf[o] = e.resid[o] + s * vv;
                } else if (e.mode == 2) {
                    float z = vv + e.bias[gn];
                    float g = 0.5f * z * (1.f + erff(z * 0.70710678118654752f));
                    e.out_h[(size_t)gm * R + gn] = (f16)g;
                } else {
                    size_t o = (size_t)gm * V + gn;
                    e.outf[o] = e.resid[o] + s * vv;
                }
            }
        }
    }
}

// ---------------------------------------------------------------- attention
// retrieved[t,d] = sum_{s>t} decay^(s-t-1) * (q_t . k_s) * v[s,d]
// grid: (T/64, B); block 256 (4 waves). Q-tile = 64 rows.
__global__ __launch_bounds__(256) void attn_kernel(const f16* __restrict__ q,
                                                   const f16* __restrict__ k,
                                                   const f16* __restrict__ vT,
                                                   f16* __restrict__ ret,
                                                   const float* __restrict__ decay_logit) {
    __shared__ f16 Ksl[64 * 264];
    __shared__ f16 Psl[64 * 72];
    int tid = threadIdx.x, lane = tid & 63, wv = tid >> 6;
    int quad = lane >> 4, l16 = lane & 15;
    int b = blockIdx.y, t0 = blockIdx.x * 64;
    const f16* qb = q + (size_t)b * T * D;
    const f16* kb = k + (size_t)b * T * D;
    const f16* vb = vT + (size_t)b * D * T;
    f16* rb = ret + (size_t)b * T * D;

    float dl = decay_logit[0];
    float decay = 1.f / (1.f + expf(-dl));
    float l2d = log2f(decay);

    // preload this wave's Q fragments (rows t0+16*wv .. +15), K=256 -> 8 frags
    int tq = t0 + 16 * wv + l16;
    f16x8 qf[8];
    for (int kk = 0; kk < 8; kk++)
        qf[kk] = *(const f16x8*)&qb[(size_t)tq * D + kk * 32 + quad * 8];

    f32x4 acc2[4][4] = {};   // retrieved[0:64][64*wv : 64*wv+64]

    for (int s0 = t0; s0 < T; s0 += 64) {
        __syncthreads();
        // stage K tile (rows s0..s0+63, 256 cols) into LDS
        for (int p = 0; p < 8; p++) {
            int e0 = p * 2048 + tid * 8;
            int rr = e0 >> 8, cc = e0 & 255;
            *(f16x8*)&Ksl[rr * 264 + cc] = *(const f16x8*)&kb[(size_t)(s0 + rr) * D + cc];
        }
        __syncthreads();
        // GEMM1: S[16 rows of this wave][64 s] = Q . K^T
        f32x4 sacc[4] = {};
        for (int ni = 0; ni < 4; ni++) {
            for (int kk = 0; kk < 8; kk++) {
                f16x8 bf = *(const f16x8*)&Ksl[(16 * ni + l16) * 264 + kk * 32 + quad * 8];
                sacc[ni] = MFMA16(qf[kk], bf, sacc[ni]);
            }
        }
        // apply decay weights, write P (f16) to LDS
        for (int ni = 0; ni < 4; ni++) {
            int s_ = s0 + 16 * ni + l16;
            for (int i = 0; i < 4; i++) {
                int t_ = t0 + 16 * wv + quad * 4 + i;
                int diff = s_ - t_;
                float w = (diff > 0) ? exp2f((float)(diff - 1) * l2d) : 0.f;
                Psl[(16 * wv + quad * 4 + i) * 72 + 16 * ni + l16] = (f16)(sacc[ni][i] * w);
            }
        }
        __syncthreads();
        // GEMM2: retrieved[0:64][wave's 64 d-cols] += P(64x64) . V(64xD)
        for (int kk = 0; kk < 2; kk++) {
            f16x8 pa[4], vf[4];
            for (int mi = 0; mi < 4; mi++)
                pa[mi] = *(const f16x8*)&Psl[(16 * mi + l16) * 72 + kk * 32 + quad * 8];
            for (int ni = 0; ni < 4; ni++)
                vf[ni] = *(const f16x8*)&vb[(size_t)(64 * wv + 16 * ni + l16) * T + s0 + kk * 32 + quad * 8];
            for (int mi = 0; mi < 4; mi++)
                for (int ni = 0; ni < 4; ni++)
                    acc2[mi][ni] = MFMA16(pa[mi], vf[ni], acc2[mi][ni]);
        }
    }

    for (int mi = 0; mi < 4; mi++) {
        for (int ni = 0; ni < 4; ni++) {
            int t_ = t0 + 16 * mi + quad * 4;
            int d_ = 64 * wv + 16 * ni + l16;
            for (int i = 0; i < 4; i++)
                rb[(size_t)(t_ + i) * D + d_] = (f16)acc2[mi][ni][i];
        }
    }
}

// ---------------------------------------------------------------- launch
extern "C" void kernel_launch(void* const* d_in, const int* in_sizes, int n_in,
                              void* d_out, int out_size, void* d_ws, size_t ws_size,
                              hipStream_t stream) {
    const float* x           = (const float*)d_in[0];
    const float* Wq          = (const float*)d_in[1];
    const float* Wk          = (const float*)d_in[2];
    const float* Wv          = (const float*)d_in[3];
    const float* Wo          = (const float*)d_in[4];
    const float* decay_logit = (const float*)d_in[5];
    const float* q_out_scale = (const float*)d_in[6];
    const float* Wdown       = (const float*)d_in[7];
    const float* Wup         = (const float*)d_in[8];
    const float* t_bias      = (const float*)d_in[9];
    const float* t_out_scale = (const float*)d_in[10];
    const float* q_scale     = (const float*)d_in[11];
    const float* t_scale     = (const float*)d_in[12];

    char* ws = (char*)d_ws;
    f16* Wqkv16  = (f16*)ws;  ws += (size_t)768 * V * 2;       // 3 MiB
    f16* Wo16    = (f16*)ws;  ws += (size_t)V * D * 2;         // 1 MiB
    f16* Wdown16 = (f16*)ws;  ws += (size_t)R * V * 2;         // 2 MiB
    f16* Wup16   = (f16*)ws;  ws += (size_t)V * R * 2;         // 2 MiB
    f16* xn16    = (f16*)ws;  ws += (size_t)M * V * 2;         // 32 MiB (reused as xn2)
    f16* q16     = (f16*)ws;  ws += (size_t)M * D * 2;         // 4 MiB (reused by h16)
    f16* k16     = (f16*)ws;  ws += (size_t)M * D * 2;         // 4 MiB (reused by h16)
    f16* vT16    = (f16*)ws;  ws += (size_t)Bsz * D * T * 2;   // 4 MiB
    f16* ret16   = (f16*)ws;  ws += (size_t)M * D * 2;         // 4 MiB
    float* x2    = (float*)ws; ws += (size_t)M * V * 4;        // 64 MiB
    f16* h16     = q16;  // reuse q16+k16 region (8 MiB) after attention

    float* out = (float*)d_out;

    // 1. convert weights to f16
    conv_f32_f16<<<dim3((D * V) / 1024), 256, 0, stream>>>(Wq, Wqkv16, D * V);
    conv_f32_f16<<<dim3((D * V) / 1024), 256, 0, stream>>>(Wk, Wqkv16 + (size_t)D * V, D * V);
    conv_f32_f16<<<dim3((D * V) / 1024), 256, 0, stream>>>(Wv, Wqkv16 + (size_t)2 * D * V, D * V);
    conv_f32_f16<<<dim3((V * D) / 1024), 256, 0, stream>>>(Wo, Wo16, V * D);
    conv_f32_f16<<<dim3((R * V) / 1024), 256, 0, stream>>>(Wdown, Wdown16, R * V);
    conv_f32_f16<<<dim3((V * R) / 1024), 256, 0, stream>>>(Wup, Wup16, V * R);

    // 2. rmsnorm(x) -> xn16
    rmsnorm_kernel<<<dim3(M), 256, 0, stream>>>(x, xn16);

    // 3. QKV GEMM (fused, N=768)
    {
        GemmEpi e = {};
        e.mode = 0; e.out_q = q16; e.out_k = k16; e.out_vT = vT16;
        gemm_nt<<<dim3(M / 128, 768 / 128), 256, 0, stream>>>(xn16, Wqkv16, V, e);
    }

    // 4. fused decay-attention -> ret16
    attn_kernel<<<dim3(T / 64, Bsz), 256, 0, stream>>>(q16, k16, vT16, ret16, decay_logit);

    // 5. Wo GEMM + residual: x2 = x + qs*qos*(ret @ Wo^T)
    {
        GemmEpi e = {};
        e.mode = 1; e.resid = x; e.outf = x2; e.sA = q_scale; e.sB = q_out_scale;
        gemm_nt<<<dim3(M / 128, V / 128), 256, 0, stream>>>(ret16, Wo16, D, e);
    }

    // 6. rmsnorm(x2) -> xn16 (reuse)
    rmsnorm_kernel<<<dim3(M), 256, 0, stream>>>(x2, xn16);

    // 7. Wdown GEMM + bias + exact gelu -> h16
    {
        GemmEpi e = {};
        e.mode = 2; e.out_h = h16; e.bias = t_bias;
        gemm_nt<<<dim3(M / 128, R / 128), 256, 0, stream>>>(xn16, Wdown16, V, e);
    }

    // 8. Wup GEMM + residual: out = x2 + ts*tos*(h @ Wup^T)
    {
        GemmEpi e = {};
        e.mode = 3; e.resid = x2; e.outf = out; e.sA = t_scale; e.sB = t_out_scale;
        gemm_nt<<<dim3(M / 128, V / 128), 256, 0, stream>>>(h16, Wup16, R, e);
    }
}

// Round 2
// 543.112 us; speedup vs baseline: 3.3085x; 3.3085x over previous
//
#include <hip/hip_runtime.h>
#include <cmath>

typedef _Float16 f16;
typedef _Float16 f16x8 __attribute__((ext_vector_type(8)));
typedef _Float16 f16x4 __attribute__((ext_vector_type(4)));
typedef float f32x4 __attribute__((ext_vector_type(4)));

#define MFMA16(a, b, c) __builtin_amdgcn_mfma_f32_16x16x32_f16(a, b, c, 0, 0, 0)

static constexpr int Bsz = 4;
static constexpr int T = 2048;
static constexpr int V = 2048;
static constexpr int D = 256;
static constexpr int R = 512;
static constexpr int M = Bsz * T;   // 8192

// ---------------------------------------------------------------- convert
__global__ __launch_bounds__(256) void conv_f32_f16(const float* __restrict__ src,
                                                    f16* __restrict__ dst, int n) {
    int idx = (blockIdx.x * 256 + threadIdx.x) * 4;
    if (idx < n) {
        float4 v = *(const float4*)&src[idx];
        f16x4 o;
        o[0] = (f16)v.x; o[1] = (f16)v.y; o[2] = (f16)v.z; o[3] = (f16)v.w;
        *(f16x4*)&dst[idx] = o;
    }
}

// ---------------------------------------------------------------- rmsnorm
__global__ __launch_bounds__(256) void rmsnorm_kernel(const float* __restrict__ x,
                                                      f16* __restrict__ out) {
    int row = blockIdx.x;
    const float* xr = x + (size_t)row * V;
    int tid = threadIdx.x;
    float4 v0 = ((const float4*)xr)[tid];
    float4 v1 = ((const float4*)xr)[tid + 256];
    float ss = v0.x * v0.x + v0.y * v0.y + v0.z * v0.z + v0.w * v0.w
             + v1.x * v1.x + v1.y * v1.y + v1.z * v1.z + v1.w * v1.w;
    #pragma unroll
    for (int o = 32; o > 0; o >>= 1) ss += __shfl_xor(ss, o);
    __shared__ float wsum[4];
    if ((tid & 63) == 0) wsum[tid >> 6] = ss;
    __syncthreads();
    float tot = wsum[0] + wsum[1] + wsum[2] + wsum[3];
    float s = rsqrtf(tot / (float)V + 1.1920929e-07f);
    f16* orow = out + (size_t)row * V;
    f16x4 o0, o1;
    o0[0] = (f16)(v0.x * s); o0[1] = (f16)(v0.y * s);
    o0[2] = (f16)(v0.z * s); o0[3] = (f16)(v0.w * s);
    o1[0] = (f16)(v1.x * s); o1[1] = (f16)(v1.y * s);
    o1[2] = (f16)(v1.z * s); o1[3] = (f16)(v1.w * s);
    *(f16x4*)&orow[tid * 4] = o0;
    *(f16x4*)&orow[1024 + tid * 4] = o1;
}

// ---------------------------------------------------------------- GEMM NT
// C[m,n] = sum_k A[m,k]*B[n,k];  A: MxK row-major f16, B: NxK row-major f16
// MODE 0: qkv route (N=768): cols 0-255 -> q, 256-511 -> k, 512-767 -> vT
// MODE 1: outf = resid + sA*sB*C          (x2 = x + qs*qos*C)
// MODE 2: out_h = gelu(C + bias[n])       (f16)
// MODE 3: outf = resid + sA*sB*C          (d_out = x2 + ts*tos*C)
struct GemmEpi {
    const float* resid;
    float* outf;
    f16* out_q; f16* out_k; f16* out_vT;
    f16* out_h;
    const float* bias;
    const float* sA; const float* sB;
};

template <int MODE>
__global__ __launch_bounds__(256) void gemm_nt(const f16* __restrict__ A,
                                               const f16* __restrict__ Bm,
                                               int K, GemmEpi e) {
    __shared__ f16 Asl[128 * 40];
    __shared__ f16 Bsl[128 * 40];
    int tid = threadIdx.x;
    int lane = tid & 63, wv = tid >> 6;
    int wm = wv >> 1, wn = wv & 1;
    int quad = lane >> 4, l16 = lane & 15;
    int m0 = blockIdx.x * 128, n0 = blockIdx.y * 128;
    f32x4 acc[4][4] = {};
    int r = tid >> 2, c8 = (tid & 3) << 3;

    for (int k0 = 0; k0 < K; k0 += 32) {
        f16x8 a0 = *(const f16x8*)&A[(size_t)(m0 + r) * K + k0 + c8];
        f16x8 a1 = *(const f16x8*)&A[(size_t)(m0 + r + 64) * K + k0 + c8];
        f16x8 b0 = *(const f16x8*)&Bm[(size_t)(n0 + r) * K + k0 + c8];
        f16x8 b1 = *(const f16x8*)&Bm[(size_t)(n0 + r + 64) * K + k0 + c8];
        __syncthreads();
        *(f16x8*)&Asl[r * 40 + c8] = a0;
        *(f16x8*)&Asl[(r + 64) * 40 + c8] = a1;
        *(f16x8*)&Bsl[r * 40 + c8] = b0;
        *(f16x8*)&Bsl[(r + 64) * 40 + c8] = b1;
        __syncthreads();
        f16x8 af[4], bf[4];
        #pragma unroll
        for (int i = 0; i < 4; i++)
            af[i] = *(const f16x8*)&Asl[(64 * wm + 16 * i + l16) * 40 + quad * 8];
        #pragma unroll
        for (int i = 0; i < 4; i++)
            bf[i] = *(const f16x8*)&Bsl[(64 * wn + 16 * i + l16) * 40 + quad * 8];
        #pragma unroll
        for (int mi = 0; mi < 4; mi++)
            #pragma unroll
            for (int ni = 0; ni < 4; ni++)
                acc[mi][ni] = MFMA16(af[mi], bf[ni], acc[mi][ni]);
    }

    float s = 0.f;
    if (MODE == 1 || MODE == 3) s = e.sA[0] * e.sB[0];
    #pragma unroll
    for (int mi = 0; mi < 4; mi++) {
        #pragma unroll
        for (int ni = 0; ni < 4; ni++) {
            int ml = 64 * wm + 16 * mi + quad * 4;
            int nl = 64 * wn + 16 * ni + l16;
            int gn = n0 + nl;
            #pragma unroll
            for (int i = 0; i < 4; i++) {
                int gm = m0 + ml + i;
                float vv = acc[mi][ni][i];
                if (MODE == 0) {
                    if (gn < 256) {
                        e.out_q[(size_t)gm * D + gn] = (f16)vv;
                    } else if (gn < 512) {
                        e.out_k[(size_t)gm * D + (gn - 256)] = (f16)vv;
                    } else {
                        int d = gn - 512;
                        int b = gm >> 11, t = gm & 2047;
                        e.out_vT[((size_t)b * D + d) * T + t] = (f16)vv;
                    }
                } else if (MODE == 1 || MODE == 3) {
                    size_t o = (size_t)gm * V + gn;
                    e.outf[o] = e.resid[o] + s * vv;
                } else if (MODE == 2) {
                    float z = vv + e.bias[gn];
                    float g = 0.5f * z * (1.f + erff(z * 0.70710678118654752f));
                    e.out_h[(size_t)gm * R + gn] = (f16)g;
                }
            }
        }
    }
}

// ---------------------------------------------------------------- attention
// retrieved[t,d] = sum_{s>t} decay^(s-t-1) * (q_t . k_s) * v[s,d]
// grid: (T/64, B); block 256 (4 waves). Q-tile = 64 rows.
__global__ __launch_bounds__(256) void attn_kernel(const f16* __restrict__ q,
                                                   const f16* __restrict__ k,
                                                   const f16* __restrict__ vT,
                                                   f16* __restrict__ ret,
                                                   const float* __restrict__ decay_logit) {
    __shared__ f16 Ksl[64 * 264];
    __shared__ f16 Psl[64 * 72];
    int tid = threadIdx.x, lane = tid & 63, wv = tid >> 6;
    int quad = lane >> 4, l16 = lane & 15;
    int b = blockIdx.y, t0 = blockIdx.x * 64;
    const f16* qb = q + (size_t)b * T * D;
    const f16* kb = k + (size_t)b * T * D;
    const f16* vb = vT + (size_t)b * D * T;
    f16* rb = ret + (size_t)b * T * D;

    float dl = decay_logit[0];
    float decay = 1.f / (1.f + expf(-dl));
    float l2d = log2f(decay);

    // preload this wave's Q fragments (rows t0+16*wv .. +15), K=256 -> 8 frags
    int tq = t0 + 16 * wv + l16;
    f16x8 qf[8];
    #pragma unroll
    for (int kk = 0; kk < 8; kk++)
        qf[kk] = *(const f16x8*)&qb[(size_t)tq * D + kk * 32 + quad * 8];

    f32x4 acc2[4][4] = {};   // retrieved[0:64][64*wv : 64*wv+64]

    for (int s0 = t0; s0 < T; s0 += 64) {
        __syncthreads();
        // stage K tile (rows s0..s0+63, 256 cols) into LDS
        #pragma unroll
        for (int p = 0; p < 8; p++) {
            int e0 = p * 2048 + tid * 8;
            int rr = e0 >> 8, cc = e0 & 255;
            *(f16x8*)&Ksl[rr * 264 + cc] = *(const f16x8*)&kb[(size_t)(s0 + rr) * D + cc];
        }
        __syncthreads();
        // GEMM1: S[16 rows of this wave][64 s] = Q . K^T
        f32x4 sacc[4] = {};
        #pragma unroll
        for (int ni = 0; ni < 4; ni++) {
            #pragma unroll
            for (int kk = 0; kk < 8; kk++) {
                f16x8 bf = *(const f16x8*)&Ksl[(16 * ni + l16) * 264 + kk * 32 + quad * 8];
                sacc[ni] = MFMA16(qf[kk], bf, sacc[ni]);
            }
        }
        // apply decay weights, write P (f16) to LDS
        #pragma unroll
        for (int ni = 0; ni < 4; ni++) {
            int s_ = s0 + 16 * ni + l16;
            #pragma unroll
            for (int i = 0; i < 4; i++) {
                int t_ = t0 + 16 * wv + quad * 4 + i;
                int diff = s_ - t_;
                float w = (diff > 0) ? exp2f((float)(diff - 1) * l2d) : 0.f;
                Psl[(16 * wv + quad * 4 + i) * 72 + 16 * ni + l16] = (f16)(sacc[ni][i] * w);
            }
        }
        __syncthreads();
        // GEMM2: retrieved[0:64][wave's 64 d-cols] += P(64x64) . V(64xD)
        #pragma unroll
        for (int kk = 0; kk < 2; kk++) {
            f16x8 pa[4], vf[4];
            #pragma unroll
            for (int mi = 0; mi < 4; mi++)
                pa[mi] = *(const f16x8*)&Psl[(16 * mi + l16) * 72 + kk * 32 + quad * 8];
            #pragma unroll
            for (int ni = 0; ni < 4; ni++)
                vf[ni] = *(const f16x8*)&vb[(size_t)(64 * wv + 16 * ni + l16) * T + s0 + kk * 32 + quad * 8];
            #pragma unroll
            for (int mi = 0; mi < 4; mi++)
                #pragma unroll
                for (int ni = 0; ni < 4; ni++)
                    acc2[mi][ni] = MFMA16(pa[mi], vf[ni], acc2[mi][ni]);
        }
    }

    #pragma unroll
    for (int mi = 0; mi < 4; mi++) {
        #pragma unroll
        for (int ni = 0; ni < 4; ni++) {
            int t_ = t0 + 16 * mi + quad * 4;
            int d_ = 64 * wv + 16 * ni + l16;
            #pragma unroll
            for (int i = 0; i < 4; i++)
                rb[(size_t)(t_ + i) * D + d_] = (f16)acc2[mi][ni][i];
        }
    }
}

// ---------------------------------------------------------------- launch
extern "C" void kernel_launch(void* const* d_in, const int* in_sizes, int n_in,
                              void* d_out, int out_size, void* d_ws, size_t ws_size,
                              hipStream_t stream) {
    const float* x           = (const float*)d_in[0];
    const float* Wq          = (const float*)d_in[1];
    const float* Wk          = (const float*)d_in[2];
    const float* Wv          = (const float*)d_in[3];
    const float* Wo          = (const float*)d_in[4];
    const float* decay_logit = (const float*)d_in[5];
    const float* q_out_scale = (const float*)d_in[6];
    const float* Wdown       = (const float*)d_in[7];
    const float* Wup         = (const float*)d_in[8];
    const float* t_bias      = (const float*)d_in[9];
    const float* t_out_scale = (const float*)d_in[10];
    const float* q_scale     = (const float*)d_in[11];
    const float* t_scale     = (const float*)d_in[12];

    char* ws = (char*)d_ws;
    f16* Wqkv16  = (f16*)ws;  ws += (size_t)768 * V * 2;       // 3 MiB
    f16* Wo16    = (f16*)ws;  ws += (size_t)V * D * 2;         // 1 MiB
    f16* Wdown16 = (f16*)ws;  ws += (size_t)R * V * 2;         // 2 MiB
    f16* Wup16   = (f16*)ws;  ws += (size_t)V * R * 2;         // 2 MiB
    f16* xn16    = (f16*)ws;  ws += (size_t)M * V * 2;         // 32 MiB (reused as xn2)
    f16* q16     = (f16*)ws;  ws += (size_t)M * D * 2;         // 4 MiB (reused by h16)
    f16* k16     = (f16*)ws;  ws += (size_t)M * D * 2;         // 4 MiB (reused by h16)
    f16* vT16    = (f16*)ws;  ws += (size_t)Bsz * D * T * 2;   // 4 MiB
    f16* ret16   = (f16*)ws;  ws += (size_t)M * D * 2;         // 4 MiB
    float* x2    = (float*)ws; ws += (size_t)M * V * 4;        // 64 MiB
    f16* h16     = q16;  // reuse q16+k16 region (8 MiB) after attention

    float* out = (float*)d_out;

    // 1. convert weights to f16
    conv_f32_f16<<<dim3((D * V) / 1024), 256, 0, stream>>>(Wq, Wqkv16, D * V);
    conv_f32_f16<<<dim3((D * V) / 1024), 256, 0, stream>>>(Wk, Wqkv16 + (size_t)D * V, D * V);
    conv_f32_f16<<<dim3((D * V) / 1024), 256, 0, stream>>>(Wv, Wqkv16 + (size_t)2 * D * V, D * V);
    conv_f32_f16<<<dim3((V * D) / 1024), 256, 0, stream>>>(Wo, Wo16, V * D);
    conv_f32_f16<<<dim3((R * V) / 1024), 256, 0, stream>>>(Wdown, Wdown16, R * V);
    conv_f32_f16<<<dim3((V * R) / 1024), 256, 0, stream>>>(Wup, Wup16, V * R);

    // 2. rmsnorm(x) -> xn16
    rmsnorm_kernel<<<dim3(M), 256, 0, stream>>>(x, xn16);

    // 3. QKV GEMM (fused, N=768)
    {
        GemmEpi e = {};
        e.out_q = q16; e.out_k = k16; e.out_vT = vT16;
        gemm_nt<0><<<dim3(M / 128, 768 / 128), 256, 0, stream>>>(xn16, Wqkv16, V, e);
    }

    // 4. fused decay-attention -> ret16
    attn_kernel<<<dim3(T / 64, Bsz), 256, 0, stream>>>(q16, k16, vT16, ret16, decay_logit);

    // 5. Wo GEMM + residual: x2 = x + qs*qos*(ret @ Wo^T)
    {
        GemmEpi e = {};
        e.resid = x; e.outf = x2; e.sA = q_scale; e.sB = q_out_scale;
        gemm_nt<1><<<dim3(M / 128, V / 128), 256, 0, stream>>>(ret16, Wo16, D, e);
    }

    // 6. rmsnorm(x2) -> xn16 (reuse)
    rmsnorm_kernel<<<dim3(M), 256, 0, stream>>>(x2, xn16);

    // 7. Wdown GEMM + bias + exact gelu -> h16
    {
        GemmEpi e = {};
        e.out_h = h16; e.bias = t_bias;
        gemm_nt<2><<<dim3(M / 128, R / 128), 256, 0, stream>>>(xn16, Wdown16, V, e);
    }

    // 8. Wup GEMM + residual: out = x2 + ts*tos*(h @ Wup^T)
    {
        GemmEpi e = {};
        e.resid = x2; e.outf = out; e.sA = t_scale; e.sB = t_out_scale;
        gemm_nt<3><<<dim3(M / 128, V / 128), 256, 0, stream>>>(h16, Wup16, R, e);
    }
}

// Round 3
// 414.761 us; speedup vs baseline: 4.3323x; 1.3095x over previous
//
#include <hip/hip_runtime.h>
#include <cmath>

typedef _Float16 f16;
typedef _Float16 f16x8 __attribute__((ext_vector_type(8)));
typedef _Float16 f16x4 __attribute__((ext_vector_type(4)));
typedef float f32x4 __attribute__((ext_vector_type(4)));

#define MFMA16(a, b, c) __builtin_amdgcn_mfma_f32_16x16x32_f16(a, b, c, 0, 0, 0)

static constexpr int Bsz = 4;
static constexpr int T = 2048;
static constexpr int V = 2048;
static constexpr int D = 256;
static constexpr int R = 512;
static constexpr int M = Bsz * T;   // 8192

// async global->LDS, 16B per lane; LDS dest = wave-uniform base + lane*16
__device__ __forceinline__ void load_lds16(const f16* g, f16* l) {
    __builtin_amdgcn_global_load_lds(
        (const __attribute__((address_space(1))) unsigned int*)(unsigned long long)g,
        (__attribute__((address_space(3))) unsigned int*)(unsigned int)(unsigned long long)l,
        16, 0, 0);
}

// ---------------------------------------------------------------- convert
__global__ __launch_bounds__(256) void conv_f32_f16(const float* __restrict__ src,
                                                    f16* __restrict__ dst, int n) {
    int idx = (blockIdx.x * 256 + threadIdx.x) * 4;
    if (idx < n) {
        float4 v = *(const float4*)&src[idx];
        f16x4 o;
        o[0] = (f16)v.x; o[1] = (f16)v.y; o[2] = (f16)v.z; o[3] = (f16)v.w;
        *(f16x4*)&dst[idx] = o;
    }
}

// ---------------------------------------------------------------- rmsnorm
__global__ __launch_bounds__(256) void rmsnorm_kernel(const float* __restrict__ x,
                                                      f16* __restrict__ out) {
    int row = blockIdx.x;
    const float* xr = x + (size_t)row * V;
    int tid = threadIdx.x;
    float4 v0 = ((const float4*)xr)[tid];
    float4 v1 = ((const float4*)xr)[tid + 256];
    float ss = v0.x * v0.x + v0.y * v0.y + v0.z * v0.z + v0.w * v0.w
             + v1.x * v1.x + v1.y * v1.y + v1.z * v1.z + v1.w * v1.w;
    #pragma unroll
    for (int o = 32; o > 0; o >>= 1) ss += __shfl_xor(ss, o);
    __shared__ float wsum[4];
    if ((tid & 63) == 0) wsum[tid >> 6] = ss;
    __syncthreads();
    float tot = wsum[0] + wsum[1] + wsum[2] + wsum[3];
    float s = rsqrtf(tot / (float)V + 1.1920929e-07f);
    f16* orow = out + (size_t)row * V;
    f16x4 o0, o1;
    o0[0] = (f16)(v0.x * s); o0[1] = (f16)(v0.y * s);
    o0[2] = (f16)(v0.z * s); o0[3] = (f16)(v0.w * s);
    o1[0] = (f16)(v1.x * s); o1[1] = (f16)(v1.y * s);
    o1[2] = (f16)(v1.z * s); o1[3] = (f16)(v1.w * s);
    *(f16x4*)&orow[tid * 4] = o0;
    *(f16x4*)&orow[1024 + tid * 4] = o1;
}

// ---------------------------------------------------------------- GEMM NT
// C[m,n] = sum_k A[m,k]*B[n,k];  A: MxK row-major f16, B: NxK row-major f16
// m97-style: global_load_lds width-16 staging, BK=32, XOR-swizzled LDS (no pad).
// LDS tile [128][32] f16; 16B slot s at row r holds global colgroup s^((r>>1)&3).
// MODE 0: qkv route (N=768): cols 0-255 -> q, 256-511 -> k, 512-767 -> vT
// MODE 1/3: outf = resid + sA*sB*C
// MODE 2: out_h = gelu(C + bias[n])       (f16)
struct GemmEpi {
    const float* resid;
    float* outf;
    f16* out_q; f16* out_k; f16* out_vT;
    f16* out_h;
    const float* bias;
    const float* sA; const float* sB;
};

template <int MODE>
__global__ __launch_bounds__(256) void gemm_nt(const f16* __restrict__ A,
                                               const f16* __restrict__ Bm,
                                               int K, GemmEpi e) {
    __shared__ f16 Asl[128 * 32];
    __shared__ f16 Bsl[128 * 32];
    int tid = threadIdx.x;
    int lane = tid & 63, wv = tid >> 6;
    int wm = wv >> 1, wn = wv & 1;
    int quad = lane >> 4, l16 = lane & 15;
    int m0 = blockIdx.x * 128, n0 = blockIdx.y * 128;
    f32x4 acc[4][4] = {};

    // staging: wave wv covers 16-row groups {wv, wv+4}. lane i -> row 16g+(i>>2),
    // global colgroup (i&3)^((i>>3)&3)  (XOR swizzle; see header comment)
    int srow = lane >> 2;
    int scg = (lane & 3) ^ ((lane >> 3) & 3);
    const f16* Ag0 = &A[(size_t)(m0 + 16 * wv + srow) * K + scg * 8];
    const f16* Ag1 = &A[(size_t)(m0 + 16 * (wv + 4) + srow) * K + scg * 8];
    const f16* Bg0 = &Bm[(size_t)(n0 + 16 * wv + srow) * K + scg * 8];
    const f16* Bg1 = &Bm[(size_t)(n0 + 16 * (wv + 4) + srow) * K + scg * 8];
    f16* Al0 = &Asl[(16 * wv) * 32];
    f16* Al1 = &Asl[(16 * (wv + 4)) * 32];
    f16* Bl0 = &Bsl[(16 * wv) * 32];
    f16* Bl1 = &Bsl[(16 * (wv + 4)) * 32];

    int fs = quad ^ ((l16 >> 1) & 3);  // read-side swizzled slot

    for (int k0 = 0; k0 < K; k0 += 32) {
        __syncthreads();
        load_lds16(Ag0 + k0, Al0);
        load_lds16(Ag1 + k0, Al1);
        load_lds16(Bg0 + k0, Bl0);
        load_lds16(Bg1 + k0, Bl1);
        __syncthreads();
        f16x8 af[4], bf[4];
        #pragma unroll
        for (int i = 0; i < 4; i++)
            af[i] = *(const f16x8*)&Asl[(64 * wm + 16 * i + l16) * 32 + fs * 8];
        #pragma unroll
        for (int i = 0; i < 4; i++)
            bf[i] = *(const f16x8*)&Bsl[(64 * wn + 16 * i + l16) * 32 + fs * 8];
        #pragma unroll
        for (int mi = 0; mi < 4; mi++)
            #pragma unroll
            for (int ni = 0; ni < 4; ni++)
                acc[mi][ni] = MFMA16(af[mi], bf[ni], acc[mi][ni]);
    }

    float s = 0.f;
    if (MODE == 1 || MODE == 3) s = e.sA[0] * e.sB[0];
    #pragma unroll
    for (int mi = 0; mi < 4; mi++) {
        #pragma unroll
        for (int ni = 0; ni < 4; ni++) {
            int ml = 64 * wm + 16 * mi + quad * 4;
            int nl = 64 * wn + 16 * ni + l16;
            int gn = n0 + nl;
            #pragma unroll
            for (int i = 0; i < 4; i++) {
                int gm = m0 + ml + i;
                float vv = acc[mi][ni][i];
                if (MODE == 0) {
                    if (gn < 256) {
                        e.out_q[(size_t)gm * D + gn] = (f16)vv;
                    } else if (gn < 512) {
                        e.out_k[(size_t)gm * D + (gn - 256)] = (f16)vv;
                    } else {
                        int d = gn - 512;
                        int b = gm >> 11, t = gm & 2047;
                        e.out_vT[((size_t)b * D + d) * T + t] = (f16)vv;
                    }
                } else if (MODE == 1 || MODE == 3) {
                    size_t o = (size_t)gm * V + gn;
                    e.outf[o] = e.resid[o] + s * vv;
                } else if (MODE == 2) {
                    float z = vv + e.bias[gn];
                    float g = 0.5f * z * (1.f + erff(z * 0.70710678118654752f));
                    e.out_h[(size_t)gm * R + gn] = (f16)g;
                }
            }
        }
    }
}

// ---------------------------------------------------------------- attention
// retrieved[t,d] = sum_{s>t} decay^(s-t-1) * (q_t . k_s) * v[s,d]
// grid: (T/64, B); block 256 (4 waves). Q-tile = 64 rows.
// Decay-window truncation: tiles with max weight < 2^-25 contribute < ~1e-5
// to ret (output scale ~10, threshold 0.2) -> skip. ~7 tiles instead of <=32.
__global__ __launch_bounds__(256) void attn_kernel(const f16* __restrict__ q,
                                                   const f16* __restrict__ k,
                                                   const f16* __restrict__ vT,
                                                   f16* __restrict__ ret,
                                                   const float* __restrict__ decay_logit) {
    __shared__ f16 Ksl[64 * 264];
    __shared__ f16 Psl[64 * 72];
    int tid = threadIdx.x, lane = tid & 63, wv = tid >> 6;
    int quad = lane >> 4, l16 = lane & 15;
    int b = blockIdx.y, t0 = blockIdx.x * 64;
    const f16* qb = q + (size_t)b * T * D;
    const f16* kb = k + (size_t)b * T * D;
    const f16* vb = vT + (size_t)b * D * T;
    f16* rb = ret + (size_t)b * T * D;

    float dl = decay_logit[0];
    float decay = 1.f / (1.f + expf(-dl));
    float l2d = log2f(decay);
    float nl2d = -l2d;

    // preload this wave's Q fragments (rows t0+16*wv .. +15), K=256 -> 8 frags
    int tq = t0 + 16 * wv + l16;
    f16x8 qf[8];
    #pragma unroll
    for (int kk = 0; kk < 8; kk++)
        qf[kk] = *(const f16x8*)&qb[(size_t)tq * D + kk * 32 + quad * 8];

    f32x4 acc2[4][4] = {};   // retrieved[0:64][64*wv : 64*wv+64]

    for (int s0 = t0; s0 < T; s0 += 64) {
        // largest weight in this tile is decay^(s0 - (t0+63) - 1); skip if < 2^-25
        if ((float)(s0 - t0 - 64) * nl2d > 25.f) break;
        __syncthreads();
        // stage K tile (rows s0..s0+63, 256 cols) into LDS
        #pragma unroll
        for (int p = 0; p < 8; p++) {
            int e0 = p * 2048 + tid * 8;
            int rr = e0 >> 8, cc = e0 & 255;
            *(f16x8*)&Ksl[rr * 264 + cc] = *(const f16x8*)&kb[(size_t)(s0 + rr) * D + cc];
        }
        __syncthreads();
        // GEMM1: S[16 rows of this wave][64 s] = Q . K^T
        f32x4 sacc[4] = {};
        #pragma unroll
        for (int ni = 0; ni < 4; ni++) {
            #pragma unroll
            for (int kk = 0; kk < 8; kk++) {
                f16x8 bf = *(const f16x8*)&Ksl[(16 * ni + l16) * 264 + kk * 32 + quad * 8];
                sacc[ni] = MFMA16(qf[kk], bf, sacc[ni]);
            }
        }
        // apply decay weights, write P (f16) to LDS
        #pragma unroll
        for (int ni = 0; ni < 4; ni++) {
            int s_ = s0 + 16 * ni + l16;
            #pragma unroll
            for (int i = 0; i < 4; i++) {
                int t_ = t0 + 16 * wv + quad * 4 + i;
                int diff = s_ - t_;
                float w = (diff > 0) ? exp2f((float)(diff - 1) * l2d) : 0.f;
                Psl[(16 * wv + quad * 4 + i) * 72 + 16 * ni + l16] = (f16)(sacc[ni][i] * w);
            }
        }
        __syncthreads();
        // GEMM2: retrieved[0:64][wave's 64 d-cols] += P(64x64) . V(64xD)
        #pragma unroll
        for (int kk = 0; kk < 2; kk++) {
            f16x8 pa[4], vf[4];
            #pragma unroll
            for (int mi = 0; mi < 4; mi++)
                pa[mi] = *(const f16x8*)&Psl[(16 * mi + l16) * 72 + kk * 32 + quad * 8];
            #pragma unroll
            for (int ni = 0; ni < 4; ni++)
                vf[ni] = *(const f16x8*)&vb[(size_t)(64 * wv + 16 * ni + l16) * T + s0 + kk * 32 + quad * 8];
            #pragma unroll
            for (int mi = 0; mi < 4; mi++)
                #pragma unroll
                for (int ni = 0; ni < 4; ni++)
                    acc2[mi][ni] = MFMA16(pa[mi], vf[ni], acc2[mi][ni]);
        }
    }

    #pragma unroll
    for (int mi = 0; mi < 4; mi++) {
        #pragma unroll
        for (int ni = 0; ni < 4; ni++) {
            int t_ = t0 + 16 * mi + quad * 4;
            int d_ = 64 * wv + 16 * ni + l16;
            #pragma unroll
            for (int i = 0; i < 4; i++)
                rb[(size_t)(t_ + i) * D + d_] = (f16)acc2[mi][ni][i];
        }
    }
}

// ---------------------------------------------------------------- launch
extern "C" void kernel_launch(void* const* d_in, const int* in_sizes, int n_in,
                              void* d_out, int out_size, void* d_ws, size_t ws_size,
                              hipStream_t stream) {
    const float* x           = (const float*)d_in[0];
    const float* Wq          = (const float*)d_in[1];
    const float* Wk          = (const float*)d_in[2];
    const float* Wv          = (const float*)d_in[3];
    const float* Wo          = (const float*)d_in[4];
    const float* decay_logit = (const float*)d_in[5];
    const float* q_out_scale = (const float*)d_in[6];
    const float* Wdown       = (const float*)d_in[7];
    const float* Wup         = (const float*)d_in[8];
    const float* t_bias      = (const float*)d_in[9];
    const float* t_out_scale = (const float*)d_in[10];
    const float* q_scale     = (const float*)d_in[11];
    const float* t_scale     = (const float*)d_in[12];

    char* ws = (char*)d_ws;
    f16* Wqkv16  = (f16*)ws;  ws += (size_t)768 * V * 2;       // 3 MiB
    f16* Wo16    = (f16*)ws;  ws += (size_t)V * D * 2;         // 1 MiB
    f16* Wdown16 = (f16*)ws;  ws += (size_t)R * V * 2;         // 2 MiB
    f16* Wup16   = (f16*)ws;  ws += (size_t)V * R * 2;         // 2 MiB
    f16* xn16    = (f16*)ws;  ws += (size_t)M * V * 2;         // 32 MiB (reused as xn2)
    f16* q16     = (f16*)ws;  ws += (size_t)M * D * 2;         // 4 MiB (reused by h16)
    f16* k16     = (f16*)ws;  ws += (size_t)M * D * 2;         // 4 MiB (reused by h16)
    f16* vT16    = (f16*)ws;  ws += (size_t)Bsz * D * T * 2;   // 4 MiB
    f16* ret16   = (f16*)ws;  ws += (size_t)M * D * 2;         // 4 MiB
    float* x2    = (float*)ws; ws += (size_t)M * V * 4;        // 64 MiB
    f16* h16     = q16;  // reuse q16+k16 region (8 MiB) after attention

    float* out = (float*)d_out;

    // 1. convert weights to f16
    conv_f32_f16<<<dim3((D * V) / 1024), 256, 0, stream>>>(Wq, Wqkv16, D * V);
    conv_f32_f16<<<dim3((D * V) / 1024), 256, 0, stream>>>(Wk, Wqkv16 + (size_t)D * V, D * V);
    conv_f32_f16<<<dim3((D * V) / 1024), 256, 0, stream>>>(Wv, Wqkv16 + (size_t)2 * D * V, D * V);
    conv_f32_f16<<<dim3((V * D) / 1024), 256, 0, stream>>>(Wo, Wo16, V * D);
    conv_f32_f16<<<dim3((R * V) / 1024), 256, 0, stream>>>(Wdown, Wdown16, R * V);
    conv_f32_f16<<<dim3((V * R) / 1024), 256, 0, stream>>>(Wup, Wup16, V * R);

    // 2. rmsnorm(x) -> xn16
    rmsnorm_kernel<<<dim3(M), 256, 0, stream>>>(x, xn16);

    // 3. QKV GEMM (fused, N=768)
    {
        GemmEpi e = {};
        e.out_q = q16; e.out_k = k16; e.out_vT = vT16;
        gemm_nt<0><<<dim3(M / 128, 768 / 128), 256, 0, stream>>>(xn16, Wqkv16, V, e);
    }

    // 4. fused decay-attention -> ret16
    attn_kernel<<<dim3(T / 64, Bsz), 256, 0, stream>>>(q16, k16, vT16, ret16, decay_logit);

    // 5. Wo GEMM + residual: x2 = x + qs*qos*(ret @ Wo^T)
    {
        GemmEpi e = {};
        e.resid = x; e.outf = x2; e.sA = q_scale; e.sB = q_out_scale;
        gemm_nt<1><<<dim3(M / 128, V / 128), 256, 0, stream>>>(ret16, Wo16, D, e);
    }

    // 6. rmsnorm(x2) -> xn16 (reuse)
    rmsnorm_kernel<<<dim3(M), 256, 0, stream>>>(x2, xn16);

    // 7. Wdown GEMM + bias + exact gelu -> h16
    {
        GemmEpi e = {};
        e.out_h = h16; e.bias = t_bias;
        gemm_nt<2><<<dim3(M / 128, R / 128), 256, 0, stream>>>(xn16, Wdown16, V, e);
    }

    // 8. Wup GEMM + residual: out = x2 + ts*tos*(h @ Wup^T)
    {
        GemmEpi e = {};
        e.resid = x2; e.outf = out; e.sA = t_scale; e.sB = t_out_scale;
        gemm_nt<3><<<dim3(M / 128, V / 128), 256, 0, stream>>>(h16, Wup16, R, e);
    }
}

// Round 5
// 325.468 us; speedup vs baseline: 5.5209x; 1.2744x over previous
//
#include <hip/hip_runtime.h>
#include <cmath>

typedef _Float16 f16;
typedef _Float16 f16x8 __attribute__((ext_vector_type(8)));
typedef _Float16 f16x4 __attribute__((ext_vector_type(4)));
typedef float f32x4 __attribute__((ext_vector_type(4)));

#define MFMA16(a, b, c) __builtin_amdgcn_mfma_f32_16x16x32_f16(a, b, c, 0, 0, 0)

static constexpr int Bsz = 4;
static constexpr int T = 2048;
static constexpr int V = 2048;
static constexpr int D = 256;
static constexpr int R = 512;
static constexpr int M = Bsz * T;   // 8192

// async global->LDS, 16B per lane; LDS dest = wave-uniform base + lane*16
__device__ __forceinline__ void load_lds16(const f16* g, f16* l) {
    __builtin_amdgcn_global_load_lds(
        (const __attribute__((address_space(1))) unsigned int*)(unsigned long long)g,
        (__attribute__((address_space(3))) unsigned int*)(unsigned int)(unsigned long long)l,
        16, 0, 0);
}

// ---------------------------------------------------------------- convert
// all 6 weight matrices in one launch; dst regions are contiguous in ws.
// total elements = 3*524288 + 524288 + 1048576 + 1048576 = 4194304 -> 4096 blocks
__global__ __launch_bounds__(256) void conv_all(const float* __restrict__ s0,
                                                const float* __restrict__ s1,
                                                const float* __restrict__ s2,
                                                const float* __restrict__ s3,
                                                const float* __restrict__ s4,
                                                const float* __restrict__ s5,
                                                f16* __restrict__ dst) {
    int idx = (blockIdx.x * 256 + threadIdx.x) * 4;
    if (idx >= 4194304) return;
    const float* src; int off;
    if      (idx <  524288) { src = s0; off = idx; }
    else if (idx < 1048576) { src = s1; off = idx - 524288; }
    else if (idx < 1572864) { src = s2; off = idx - 1048576; }
    else if (idx < 2097152) { src = s3; off = idx - 1572864; }
    else if (idx < 3145728) { src = s4; off = idx - 2097152; }
    else                    { src = s5; off = idx - 3145728; }
    float4 v = *(const float4*)&src[off];
    f16x4 o;
    o[0] = (f16)v.x; o[1] = (f16)v.y; o[2] = (f16)v.z; o[3] = (f16)v.w;
    *(f16x4*)&dst[idx] = o;
}

// ---------------------------------------------------------------- rmsnorm (fp32 in)
__global__ __launch_bounds__(256) void rmsnorm_kernel(const float* __restrict__ x,
                                                      f16* __restrict__ out) {
    int row = blockIdx.x;
    const float* xr = x + (size_t)row * V;
    int tid = threadIdx.x;
    float4 v0 = ((const float4*)xr)[tid];
    float4 v1 = ((const float4*)xr)[tid + 256];
    float ss = v0.x * v0.x + v0.y * v0.y + v0.z * v0.z + v0.w * v0.w
             + v1.x * v1.x + v1.y * v1.y + v1.z * v1.z + v1.w * v1.w;
    #pragma unroll
    for (int o = 32; o > 0; o >>= 1) ss += __shfl_xor(ss, o);
    __shared__ float wsum[4];
    if ((tid & 63) == 0) wsum[tid >> 6] = ss;
    __syncthreads();
    float tot = wsum[0] + wsum[1] + wsum[2] + wsum[3];
    float s = rsqrtf(tot / (float)V + 1.1920929e-07f);
    f16* orow = out + (size_t)row * V;
    f16x4 o0, o1;
    o0[0] = (f16)(v0.x * s); o0[1] = (f16)(v0.y * s);
    o0[2] = (f16)(v0.z * s); o0[3] = (f16)(v0.w * s);
    o1[0] = (f16)(v1.x * s); o1[1] = (f16)(v1.y * s);
    o1[2] = (f16)(v1.z * s); o1[3] = (f16)(v1.w * s);
    *(f16x4*)&orow[tid * 4] = o0;
    *(f16x4*)&orow[1024 + tid * 4] = o1;
}

// ---------------------------------------------------------------- rmsnorm (f16 in)
__global__ __launch_bounds__(256) void rmsnorm_f16(const f16* __restrict__ x,
                                                   f16* __restrict__ out) {
    int row = blockIdx.x;
    int tid = threadIdx.x;
    const f16* xr = x + (size_t)row * V;
    f16x8 v = *(const f16x8*)&xr[tid * 8];
    float f[8];
    float ss = 0.f;
    #pragma unroll
    for (int j = 0; j < 8; j++) { f[j] = (float)v[j]; ss += f[j] * f[j]; }
    #pragma unroll
    for (int o = 32; o > 0; o >>= 1) ss += __shfl_xor(ss, o);
    __shared__ float wsum[4];
    if ((tid & 63) == 0) wsum[tid >> 6] = ss;
    __syncthreads();
    float tot = wsum[0] + wsum[1] + wsum[2] + wsum[3];
    float s = rsqrtf(tot / (float)V + 1.1920929e-07f);
    f16x8 o;
    #pragma unroll
    for (int j = 0; j < 8; j++) o[j] = (f16)(f[j] * s);
    *(f16x8*)&out[(size_t)row * V + tid * 8] = o;
}

// ---------------------------------------------------------------- GEMM NT
// C[m,n] = sum_k A[m,k]*B[n,k];  A: MxK row-major f16, B: NxK row-major f16
// Double-buffered global_load_lds staging; raw s_barrier + manual vmcnt so the
// prefetch DMAs stay in flight across the barrier (no implicit vmcnt(0) drain).
// XOR-swizzled LDS tile [128][32] f16, slot s at row r holds colgroup s^((r>>1)&3).
// MODE 0: qkv route (N=768): cols 0-255 -> q, 256-511 -> k, 512-767 -> vT
// MODE 1: outh = (f16)(residf + sA*sB*C)      (x2 f16 = x fp32 + ...)
// MODE 2: out_h = gelu(C + bias[n])           (f16)
// MODE 3: outf = (f32)residh + sA*sB*C        (d_out fp32 = x2 f16 + ...)
struct GemmEpi {
    const float* residf;
    const f16* residh;
    float* outf;
    f16* outh;
    f16* out_q; f16* out_k; f16* out_vT;
    f16* out_h;
    const float* bias;
    const float* sA; const float* sB;
};

template <int MODE>
__global__ __launch_bounds__(256) void gemm_nt(const f16* __restrict__ A,
                                               const f16* __restrict__ Bm,
                                               int K, GemmEpi e) {
    __shared__ f16 Asl[2][128 * 32];
    __shared__ f16 Bsl[2][128 * 32];
    int tid = threadIdx.x;
    int lane = tid & 63, wv = tid >> 6;
    int wm = wv >> 1, wn = wv & 1;
    int quad = lane >> 4, l16 = lane & 15;
    int m0 = blockIdx.x * 128, n0 = blockIdx.y * 128;
    f32x4 acc[4][4] = {};

    // staging: wave wv covers 16-row groups {wv, wv+4}. lane i -> row 16g+(i>>2),
    // global colgroup (i&3)^((i>>3)&3)  (XOR swizzle)
    int srow = lane >> 2;
    int scg = (lane & 3) ^ ((lane >> 3) & 3);
    const f16* Ag0 = &A[(size_t)(m0 + 16 * wv + srow) * K + scg * 8];
    const f16* Ag1 = &A[(size_t)(m0 + 16 * (wv + 4) + srow) * K + scg * 8];
    const f16* Bg0 = &Bm[(size_t)(n0 + 16 * wv + srow) * K + scg * 8];
    const f16* Bg1 = &Bm[(size_t)(n0 + 16 * (wv + 4) + srow) * K + scg * 8];
    int lo0 = (16 * wv) * 32, lo1 = (16 * (wv + 4)) * 32;

    int fs = quad ^ ((l16 >> 1) & 3);  // read-side swizzled slot
    int niter = K >> 5;

    // prologue: stage tile 0 into buffer 0
    load_lds16(Ag0, &Asl[0][lo0]);
    load_lds16(Ag1, &Asl[0][lo1]);
    load_lds16(Bg0, &Bsl[0][lo0]);
    load_lds16(Bg1, &Bsl[0][lo1]);

    for (int i = 0; i < niter; i++) {
        int cur = i & 1;
        __builtin_amdgcn_s_barrier();   // all waves done reading buf[cur^1]
        if (i + 1 < niter) {
            int k0 = (i + 1) << 5;
            int nb = cur ^ 1;
            load_lds16(Ag0 + k0, &Asl[nb][lo0]);
            load_lds16(Ag1 + k0, &Asl[nb][lo1]);
            load_lds16(Bg0 + k0, &Bsl[nb][lo0]);
            load_lds16(Bg1 + k0, &Bsl[nb][lo1]);
            asm volatile("s_waitcnt vmcnt(4)" ::: "memory");  // cur tile done, prefetch in flight
        } else {
            asm volatile("s_waitcnt vmcnt(0)" ::: "memory");
        }
        __builtin_amdgcn_s_barrier();   // everyone's cur tile loads complete
        f16x8 af[4], bf[4];
        #pragma unroll
        for (int j = 0; j < 4; j++)
            af[j] = *(const f16x8*)&Asl[cur][(64 * wm + 16 * j + l16) * 32 + fs * 8];
        #pragma unroll
        for (int j = 0; j < 4; j++)
            bf[j] = *(const f16x8*)&Bsl[cur][(64 * wn + 16 * j + l16) * 32 + fs * 8];
        #pragma unroll
        for (int mi = 0; mi < 4; mi++)
            #pragma unroll
            for (int ni = 0; ni < 4; ni++)
                acc[mi][ni] = MFMA16(af[mi], bf[ni], acc[mi][ni]);
    }

    float s = 0.f;
    if (MODE == 1 || MODE == 3) s = e.sA[0] * e.sB[0];
    #pragma unroll
    for (int mi = 0; mi < 4; mi++) {
        #pragma unroll
        for (int ni = 0; ni < 4; ni++) {
            int ml = 64 * wm + 16 * mi + quad * 4;
            int nl = 64 * wn + 16 * ni + l16;
            int gn = n0 + nl;
            #pragma unroll
            for (int i = 0; i < 4; i++) {
                int gm = m0 + ml + i;
                float vv = acc[mi][ni][i];
                if (MODE == 0) {
                    if (gn < 256) {
                        e.out_q[(size_t)gm * D + gn] = (f16)vv;
                    } else if (gn < 512) {
                        e.out_k[(size_t)gm * D + (gn - 256)] = (f16)vv;
                    } else {
                        int d = gn - 512;
                        int b = gm >> 11, t = gm & 2047;
                        e.out_vT[((size_t)b * D + d) * T + t] = (f16)vv;
                    }
                } else if (MODE == 1) {
                    size_t o = (size_t)gm * V + gn;
                    e.outh[o] = (f16)(e.residf[o] + s * vv);
                } else if (MODE == 2) {
                    float z = vv + e.bias[gn];
                    float g = 0.5f * z * (1.f + erff(z * 0.70710678118654752f));
                    e.out_h[(size_t)gm * R + gn] = (f16)g;
                } else {
                    size_t o = (size_t)gm * V + gn;
                    e.outf[o] = (float)e.residh[o] + s * vv;
                }
            }
        }
    }
}

// ---------------------------------------------------------------- attention
// retrieved[t,d] = sum_{s>t} decay^(s-t-1) * (q_t . k_s) * v[s,d]
// grid: (T/64, B); block 256 (4 waves). Q-tile = 64 rows.
// Decay-window truncation: tiles with max weight < 2^-25 contribute < ~1e-5.
__global__ __launch_bounds__(256) void attn_kernel(const f16* __restrict__ q,
                                                   const f16* __restrict__ k,
                                                   const f16* __restrict__ vT,
                                                   f16* __restrict__ ret,
                                                   const float* __restrict__ decay_logit) {
    __shared__ f16 Ksl[64 * 264];
    __shared__ f16 Psl[64 * 72];
    int tid = threadIdx.x, lane = tid & 63, wv = tid >> 6;
    int quad = lane >> 4, l16 = lane & 15;
    int b = blockIdx.y, t0 = blockIdx.x * 64;
    const f16* qb = q + (size_t)b * T * D;
    const f16* kb = k + (size_t)b * T * D;
    const f16* vb = vT + (size_t)b * D * T;
    f16* rb = ret + (size_t)b * T * D;

    float dl = decay_logit[0];
    float decay = 1.f / (1.f + expf(-dl));
    float l2d = log2f(decay);
    float nl2d = -l2d;

    int tq = t0 + 16 * wv + l16;
    f16x8 qf[8];
    #pragma unroll
    for (int kk = 0; kk < 8; kk++)
        qf[kk] = *(const f16x8*)&qb[(size_t)tq * D + kk * 32 + quad * 8];

    f32x4 acc2[4][4] = {};   // retrieved[0:64][64*wv : 64*wv+64]

    for (int s0 = t0; s0 < T; s0 += 64) {
        if ((float)(s0 - t0 - 64) * nl2d > 25.f) break;
        __syncthreads();
        #pragma unroll
        for (int p = 0; p < 8; p++) {
            int e0 = p * 2048 + tid * 8;
            int rr = e0 >> 8, cc = e0 & 255;
            *(f16x8*)&Ksl[rr * 264 + cc] = *(const f16x8*)&kb[(size_t)(s0 + rr) * D + cc];
        }
        __syncthreads();
        f32x4 sacc[4] = {};
        #pragma unroll
        for (int ni = 0; ni < 4; ni++) {
            #pragma unroll
            for (int kk = 0; kk < 8; kk++) {
                f16x8 bf = *(const f16x8*)&Ksl[(16 * ni + l16) * 264 + kk * 32 + quad * 8];
                sacc[ni] = MFMA16(qf[kk], bf, sacc[ni]);
            }
        }
        #pragma unroll
        for (int ni = 0; ni < 4; ni++) {
            int s_ = s0 + 16 * ni + l16;
            #pragma unroll
            for (int i = 0; i < 4; i++) {
                int t_ = t0 + 16 * wv + quad * 4 + i;
                int diff = s_ - t_;
                float w = (diff > 0) ? exp2f((float)(diff - 1) * l2d) : 0.f;
                Psl[(16 * wv + quad * 4 + i) * 72 + 16 * ni + l16] = (f16)(sacc[ni][i] * w);
            }
        }
        __syncthreads();
        #pragma unroll
        for (int kk = 0; kk < 2; kk++) {
            f16x8 pa[4], vf[4];
            #pragma unroll
            for (int mi = 0; mi < 4; mi++)
                pa[mi] = *(const f16x8*)&Psl[(16 * mi + l16) * 72 + kk * 32 + quad * 8];
            #pragma unroll
            for (int ni = 0; ni < 4; ni++)
                vf[ni] = *(const f16x8*)&vb[(size_t)(64 * wv + 16 * ni + l16) * T + s0 + kk * 32 + quad * 8];
            #pragma unroll
            for (int mi = 0; mi < 4; mi++)
                #pragma unroll
                for (int ni = 0; ni < 4; ni++)
                    acc2[mi][ni] = MFMA16(pa[mi], vf[ni], acc2[mi][ni]);
        }
    }

    #pragma unroll
    for (int mi = 0; mi < 4; mi++) {
        #pragma unroll
        for (int ni = 0; ni < 4; ni++) {
            int t_ = t0 + 16 * mi + quad * 4;
            int d_ = 64 * wv + 16 * ni + l16;
            #pragma unroll
            for (int i = 0; i < 4; i++)
                rb[(size_t)(t_ + i) * D + d_] = (f16)acc2[mi][ni][i];
        }
    }
}

// ---------------------------------------------------------------- launch
extern "C" void kernel_launch(void* const* d_in, const int* in_sizes, int n_in,
                              void* d_out, int out_size, void* d_ws, size_t ws_size,
                              hipStream_t stream) {
    const float* x           = (const float*)d_in[0];
    const float* Wq          = (const float*)d_in[1];
    const float* Wk          = (const float*)d_in[2];
    const float* Wv          = (const float*)d_in[3];
    const float* Wo          = (const float*)d_in[4];
    const float* decay_logit = (const float*)d_in[5];
    const float* q_out_scale = (const float*)d_in[6];
    const float* Wdown       = (const float*)d_in[7];
    const float* Wup         = (const float*)d_in[8];
    const float* t_bias      = (const float*)d_in[9];
    const float* t_out_scale = (const float*)d_in[10];
    const float* q_scale     = (const float*)d_in[11];
    const float* t_scale     = (const float*)d_in[12];

    char* ws = (char*)d_ws;
    f16* Wqkv16  = (f16*)ws;  ws += (size_t)768 * V * 2;       // 3 MiB  } contiguous
    f16* Wo16    = (f16*)ws;  ws += (size_t)V * D * 2;         // 1 MiB  } dst for
    f16* Wdown16 = (f16*)ws;  ws += (size_t)R * V * 2;         // 2 MiB  } conv_all
    f16* Wup16   = (f16*)ws;  ws += (size_t)V * R * 2;         // 2 MiB  }
    f16* xn16    = (f16*)ws;  ws += (size_t)M * V * 2;         // 32 MiB (reused as xn2)
    f16* q16     = (f16*)ws;  ws += (size_t)M * D * 2;         // 4 MiB (reused by h16)
    f16* k16     = (f16*)ws;  ws += (size_t)M * D * 2;         // 4 MiB (reused by h16)
    f16* vT16    = (f16*)ws;  ws += (size_t)Bsz * D * T * 2;   // 4 MiB
    f16* ret16   = (f16*)ws;  ws += (size_t)M * D * 2;         // 4 MiB
    f16* x2_16   = (f16*)ws;  ws += (size_t)M * V * 2;         // 32 MiB (residual stream, f16)
    f16* h16     = q16;  // reuse q16+k16 region (8 MiB) after attention

    float* out = (float*)d_out;

    // 1. convert all weights to f16 (one launch; dsts contiguous from Wqkv16)
    conv_all<<<dim3(4096), 256, 0, stream>>>(Wq, Wk, Wv, Wo, Wdown, Wup, Wqkv16);

    // 2. rmsnorm(x) -> xn16
    rmsnorm_kernel<<<dim3(M), 256, 0, stream>>>(x, xn16);

    // 3. QKV GEMM (fused, N=768)
    {
        GemmEpi e = {};
        e.out_q = q16; e.out_k = k16; e.out_vT = vT16;
        gemm_nt<0><<<dim3(M / 128, 768 / 128), 256, 0, stream>>>(xn16, Wqkv16, V, e);
    }

    // 4. fused decay-attention -> ret16
    attn_kernel<<<dim3(T / 64, Bsz), 256, 0, stream>>>(q16, k16, vT16, ret16, decay_logit);

    // 5. Wo GEMM + residual: x2 (f16) = x + qs*qos*(ret @ Wo^T)
    {
        GemmEpi e = {};
        e.residf = x; e.outh = x2_16; e.sA = q_scale; e.sB = q_out_scale;
        gemm_nt<1><<<dim3(M / 128, V / 128), 256, 0, stream>>>(ret16, Wo16, D, e);
    }

    // 6. rmsnorm(x2) -> xn16 (reuse)
    rmsnorm_f16<<<dim3(M), 256, 0, stream>>>(x2_16, xn16);

    // 7. Wdown GEMM + bias + exact gelu -> h16
    {
        GemmEpi e = {};
        e.out_h = h16; e.bias = t_bias;
        gemm_nt<2><<<dim3(M / 128, R / 128), 256, 0, stream>>>(xn16, Wdown16, V, e);
    }

    // 8. Wup GEMM + residual: out (fp32) = x2 + ts*tos*(h @ Wup^T)
    {
        GemmEpi e = {};
        e.residh = x2_16; e.outf = out; e.sA = t_scale; e.sB = t_out_scale;
        gemm_nt<3><<<dim3(M / 128, V / 128), 256, 0, stream>>>(h16, Wup16, R, e);
    }
}